// Round 10
// baseline (447.679 us; speedup 1.0000x reference)
//
#include <hip/hip_runtime.h>
#include <stdint.h>

#define LAMBDA_INIT_F 0.7836057665f   // 0.8 - 0.6*exp(-0.3*12)

typedef __bf16 bf16x8 __attribute__((ext_vector_type(8)));
typedef float  f32x4  __attribute__((ext_vector_type(4)));
typedef unsigned short u16x8 __attribute__((ext_vector_type(8)));
typedef unsigned short u16x4 __attribute__((ext_vector_type(4)));
typedef unsigned int u32x4 __attribute__((ext_vector_type(4)));

__device__ __forceinline__ unsigned short f2b(float f) {
    union { float f; unsigned u; } v; v.f = f;
    unsigned u = v.u;
    return (unsigned short)((u + 0x7fffu + ((u >> 16) & 1u)) >> 16);
}

// pack two fp32 -> two bf16 (round-half-up) in one dword: [bf(b):bf(a)]
__device__ __forceinline__ unsigned pk2(float a, float b) {
    unsigned ua = __float_as_uint(a) + 0x8000u;
    unsigned ub = __float_as_uint(b) + 0x8000u;
    return __builtin_amdgcn_perm(ub, ua, 0x07060302u);
}

#if __has_builtin(__builtin_amdgcn_exp2f)
#define EXP2(x) __builtin_amdgcn_exp2f(x)
#else
__device__ __forceinline__ float EXP2(float x) {
    float r; asm volatile("v_exp_f32 %0, %1\n\ts_nop 1" : "=v"(r) : "v"(x)); return r;
}
#endif

// global(16B/lane) -> LDS direct. LDS base must be wave-uniform; lanes land at base + lane*16.
#define GLD16(gp, sp) __builtin_amdgcn_global_load_lds( \
    (const __attribute__((address_space(1))) void*)(uintptr_t)(gp), \
    (__attribute__((address_space(3))) void*)(uint32_t)(uintptr_t)(sp), 16, 0, 0)

// ---------------- fp32 -> bf16 convert, 7 slabs of 4M elements ----------------
__global__ __launch_bounds__(256) void cvt7(const float* __restrict__ s0, const float* __restrict__ s1,
                                            const float* __restrict__ s2, const float* __restrict__ s3,
                                            const float* __restrict__ s4, const float* __restrict__ s5,
                                            const float* __restrict__ s6,
                                            unsigned short* __restrict__ dst) {
    int z = blockIdx.y;
    const float* s = z == 0 ? s0 : z == 1 ? s1 : z == 2 ? s2 : z == 3 ? s3 : z == 4 ? s4 : z == 5 ? s5 : s6;
    unsigned short* d = dst + (size_t)z * 4194304;
    size_t i = ((size_t)blockIdx.x * 256 + threadIdx.x) * 8;
    float4 a = *(const float4*)(s + i);
    float4 b = *(const float4*)(s + i + 4);
    u16x8 o;
    o[0] = f2b(a.x); o[1] = f2b(a.y); o[2] = f2b(a.z); o[3] = f2b(a.w);
    o[4] = f2b(b.x); o[5] = f2b(b.y); o[6] = f2b(b.z); o[7] = f2b(b.w);
    *(u16x8*)(d + i) = o;
}

// ---------------- QKV projection: 256x256 tile, BK=64, 8 waves, m201-style 4-phase ----------------
// ROUND-6 VERSION (verified 66.5 us): bf16 inputs via GLD16, single-buffered 64 KiB LDS,
// staging halves grouped by death time, counted vmcnt, per-phase barriers, setprio MFMA clusters.
__global__ __launch_bounds__(512, 2) void gemm_qkv(const unsigned short* __restrict__ Abase,
                                                   const unsigned short* __restrict__ Bbase,
                                                   unsigned short* __restrict__ Cb,
                                                   unsigned short* __restrict__ VT,
                                                   float alpha0) {
    __shared__ __align__(16) unsigned short As[16384];   // [kk*8192 + row*32 + col], 64B rows
    __shared__ __align__(16) unsigned short Bs[16384];
    const int tid = threadIdx.x;
    const int wid = tid >> 6, lane = tid & 63;
    const int quad = lane >> 4, l16 = lane & 15;
    const int wr = wid >> 2, wc = wid & 3;                 // wave grid 2M x 4N
    const int bid = blockIdx.x;
    const int wrk = (bid & 7) * 24 + (bid >> 3);           // bijective XCD swizzle (192 = 8*24)
    const int z = wrk >> 6;
    const int t6 = wrk & 63;
    const int m0 = (t6 >> 3) * 256, n0 = (t6 & 7) * 256;
    const unsigned short* A = Abase + (size_t)z * 4194304;
    const unsigned short* B = Bbase + (size_t)z * 4194304;
    const float alpha = (z == 0) ? alpha0 : 1.0f;

    const int sr = lane >> 2;                              // 0..15 row within 16-row slab
    const int sc = (((lane & 3) ^ ((lane >> 3) & 3)) * 8); // swizzled global colblock
    const int rsw = ((l16 >> 1) & 3);                      // read-side swizzle key

    f32x4 acc[8][4];
#pragma unroll
    for (int mi = 0; mi < 8; ++mi)
#pragma unroll
        for (int ni = 0; ni < 4; ++ni) acc[mi][ni] = f32x4{0.f, 0.f, 0.f, 0.f};

    // A-half h: rows (wid>>2)*128 + (wid&3)*16 + h*64, both kk subtiles (2 gld/thread)
    auto STAGE_AH = [&](int h, int k0) {
        const int rowbase = (wid >> 2) * 128 + (wid & 3) * 16 + h * 64;
#pragma unroll
        for (int kk = 0; kk < 2; ++kk)
            GLD16(A + (size_t)(m0 + rowbase + sr) * 2048 + k0 + kk * 32 + sc, &As[(kk * 256 + rowbase) * 32]);
    };
    // B-half h: rows (wid>>1)*64 + (wid&1)*16 + h*32
    auto STAGE_BH = [&](int h, int k0) {
        const int rowbase = (wid >> 1) * 64 + (wid & 1) * 16 + h * 32;
#pragma unroll
        for (int kk = 0; kk < 2; ++kk)
            GLD16(B + (size_t)(n0 + rowbase + sr) * 2048 + k0 + kk * 32 + sc, &Bs[(kk * 256 + rowbase) * 32]);
    };

#define LD_A(mh, i, kk) (*(const bf16x8*)&As[(kk * 256 + wr * 128 + (mh) * 64 + (i) * 16 + l16) * 32 + (quad ^ rsw) * 8])
#define LD_B(nh, jn, kk) (*(const bf16x8*)&Bs[(kk * 256 + wc * 64 + (nh) * 32 + (jn) * 16 + l16) * 32 + (quad ^ rsw) * 8])

    // prologue: stage tile 0 in queue order Ah0,Bh0 (oldest 4) then Bh1, Ah1
    STAGE_AH(0, 0); STAGE_BH(0, 0);
    STAGE_BH(1, 0);
    STAGE_AH(1, 0);
    asm volatile("s_waitcnt vmcnt(4)" ::: "memory");   // Ah0,Bh0 resident; Bh1,Ah1 in flight
    __builtin_amdgcn_s_barrier();

    for (int kt = 0; kt < 32; ++kt) {
        const int k1 = (kt + 1) * 64;
        bf16x8 af[2][4], b0[2][2], b1[2][2];

        // ---- P1: reads Ah0+Bh0(kt); MFMA quadrant (0,0); no staging
#pragma unroll
        for (int kk = 0; kk < 2; ++kk) {
#pragma unroll
            for (int i = 0; i < 4; ++i) af[kk][i] = LD_A(0, i, kk);
#pragma unroll
            for (int jn = 0; jn < 2; ++jn) b0[kk][jn] = LD_B(0, jn, kk);
        }
        __builtin_amdgcn_s_barrier();
        __builtin_amdgcn_s_setprio(1);
#pragma unroll
        for (int i = 0; i < 4; ++i)
#pragma unroll
            for (int jn = 0; jn < 2; ++jn)
#pragma unroll
                for (int kk = 0; kk < 2; ++kk)
                    acc[i][jn] = __builtin_amdgcn_mfma_f32_16x16x32_bf16(af[kk][i], b0[kk][jn], acc[i][jn], 0, 0, 0);
        __builtin_amdgcn_s_setprio(0);
        asm volatile("s_waitcnt vmcnt(2)" ::: "memory");   // Bh1(kt) resident for P2
        __builtin_amdgcn_s_barrier();

        // ---- P2: reads Bh1(kt); stage Ah0,Bh0(kt+1) into dead regions; MFMA (0,1)
#pragma unroll
        for (int kk = 0; kk < 2; ++kk)
#pragma unroll
            for (int jn = 0; jn < 2; ++jn) b1[kk][jn] = LD_B(1, jn, kk);
        if (kt < 31) { STAGE_AH(0, k1); STAGE_BH(0, k1); }
        __builtin_amdgcn_s_barrier();
        __builtin_amdgcn_s_setprio(1);
#pragma unroll
        for (int i = 0; i < 4; ++i)
#pragma unroll
            for (int jn = 0; jn < 2; ++jn)
#pragma unroll
                for (int kk = 0; kk < 2; ++kk)
                    acc[i][2 + jn] = __builtin_amdgcn_mfma_f32_16x16x32_bf16(af[kk][i], b1[kk][jn], acc[i][2 + jn], 0, 0, 0);
        __builtin_amdgcn_s_setprio(0);
        if (kt < 31) asm volatile("s_waitcnt vmcnt(4)" ::: "memory");  // Ah1(kt) resident for P3
        else         asm volatile("s_waitcnt vmcnt(0)" ::: "memory");
        __builtin_amdgcn_s_barrier();

        // ---- P3: reads Ah1(kt); stage Bh1(kt+1); MFMA (1,1)
#pragma unroll
        for (int kk = 0; kk < 2; ++kk)
#pragma unroll
            for (int i = 0; i < 4; ++i) af[kk][i] = LD_A(1, i, kk);
        if (kt < 31) STAGE_BH(1, k1);
        __builtin_amdgcn_s_barrier();
        __builtin_amdgcn_s_setprio(1);
#pragma unroll
        for (int i = 0; i < 4; ++i)
#pragma unroll
            for (int jn = 0; jn < 2; ++jn)
#pragma unroll
                for (int kk = 0; kk < 2; ++kk)
                    acc[4 + i][2 + jn] = __builtin_amdgcn_mfma_f32_16x16x32_bf16(af[kk][i], b1[kk][jn], acc[4 + i][2 + jn], 0, 0, 0);
        __builtin_amdgcn_s_setprio(0);
        __builtin_amdgcn_s_barrier();

        // ---- P4: register-only MFMA (1,0); stage Ah1(kt+1)
        if (kt < 31) STAGE_AH(1, k1);
        __builtin_amdgcn_s_barrier();
        __builtin_amdgcn_s_setprio(1);
#pragma unroll
        for (int i = 0; i < 4; ++i)
#pragma unroll
            for (int jn = 0; jn < 2; ++jn)
#pragma unroll
                for (int kk = 0; kk < 2; ++kk)
                    acc[4 + i][jn] = __builtin_amdgcn_mfma_f32_16x16x32_bf16(af[kk][i], b0[kk][jn], acc[4 + i][jn], 0, 0, 0);
        __builtin_amdgcn_s_setprio(0);
        asm volatile("s_waitcnt vmcnt(4)" ::: "memory");   // Ah0,Bh0(kt+1) resident for next P1
        __builtin_amdgcn_s_barrier();
    }
#undef LD_A
#undef LD_B

    if (z == 2) {
        // transposed write: VT[n][pi(m)], packed 4 bf16 (m-consecutive, pi keeps low 2 bits)
#pragma unroll
        for (int mi = 0; mi < 8; ++mi)
#pragma unroll
            for (int ni = 0; ni < 4; ++ni) {
                int n = n0 + wc * 64 + ni * 16 + l16;
                int m = m0 + wr * 128 + mi * 16 + quad * 4;
                int sm = (m & ~31) | ((m & 12) << 1) | ((m & 16) >> 2) | (m & 3);
                u16x4 o;
#pragma unroll
                for (int r = 0; r < 4; ++r) o[r] = f2b(acc[mi][ni][r]);
                *(u16x4*)&VT[(size_t)n * 2048 + sm] = o;
            }
    } else {
        unsigned short* Cz = Cb + (size_t)z * 4194304;
#pragma unroll
        for (int mi = 0; mi < 8; ++mi)
#pragma unroll
            for (int ni = 0; ni < 4; ++ni)
#pragma unroll
                for (int r = 0; r < 4; ++r) {
                    int row = m0 + wr * 128 + mi * 16 + quad * 4 + r;
                    int col = n0 + wc * 64 + ni * 16 + l16;
                    Cz[(size_t)row * 2048 + col] = f2b(acc[mi][ni][r] * alpha);
                }
    }
}

// ---------------- output projection GEMM (NT=128 tile, triple-buffered) ----------------
template <int OUT_BF16, int NT, int DO_VT, int WPB>
__global__ __launch_bounds__(256, WPB) void gemm_bt(const unsigned short* __restrict__ Abase,
                                                    const unsigned short* __restrict__ Bbase,
                                                    void* __restrict__ Cbase,
                                                    unsigned short* __restrict__ VT,
                                                    float alpha0) {
    constexpr int MI = (NT == 128) ? 4 : 2;
    __shared__ __align__(16) unsigned short As[3][128 * 32];
    __shared__ __align__(16) unsigned short Bs[3][NT * 32];
    const int tid = threadIdx.x;
    const int w = tid >> 6, lane = tid & 63;
    const int quad = lane >> 4, l16 = lane & 15;
    const int b = blockIdx.z;
    const unsigned short* A = Abase + (size_t)b * 4194304;
    const unsigned short* B = Bbase + (size_t)b * 4194304;
    const float alpha = (b == 0) ? alpha0 : 1.0f;
    const int m0 = blockIdx.y * 128, n0 = blockIdx.x * NT;
    const int wm = (NT == 128) ? (w >> 1) * 64 : w * 32;
    const int wn = (NT == 128) ? (w & 1) * 64 : 0;
    const int sr = lane >> 2;                              // 0..15 row within 16-row slab
    const int sc = (((lane & 3) ^ ((lane >> 3) & 3)) * 8); // swizzled global colblock
    const int rsw = ((l16 >> 1) & 3);                      // read-side swizzle key

    f32x4 zz = {0.f, 0.f, 0.f, 0.f};
    f32x4 acc[MI][4];
#pragma unroll
    for (int i = 0; i < MI; ++i)
#pragma unroll
        for (int jn = 0; jn < 4; ++jn) acc[i][jn] = zz;

    auto STAGE = [&](int bsel, int k0) {
        GLD16(A + (size_t)(m0 + w * 16 + sr) * 2048 + k0 + sc,      &As[bsel][(w * 16) * 32]);
        GLD16(A + (size_t)(m0 + 64 + w * 16 + sr) * 2048 + k0 + sc, &As[bsel][(64 + w * 16) * 32]);
        if (NT == 128) {
            GLD16(B + (size_t)(n0 + w * 16 + sr) * 2048 + k0 + sc,      &Bs[bsel][(w * 16) * 32]);
            GLD16(B + (size_t)(n0 + 64 + w * 16 + sr) * 2048 + k0 + sc, &Bs[bsel][(64 + w * 16) * 32]);
        } else {
            GLD16(B + (size_t)(n0 + w * 16 + sr) * 2048 + k0 + sc, &Bs[bsel][(w * 16) * 32]);
        }
    };

    STAGE(0, 0);
    STAGE(1, 32);
    for (int c = 0; c < 64; ++c) {
        const int cur = c % 3;
        if (c < 62) {
            STAGE((c + 2) % 3, (c + 2) * 32);
            if (NT == 128) asm volatile("s_waitcnt vmcnt(8)" ::: "memory");
            else           asm volatile("s_waitcnt vmcnt(6)" ::: "memory");
        } else if (c == 62) {
            if (NT == 128) asm volatile("s_waitcnt vmcnt(4)" ::: "memory");
            else           asm volatile("s_waitcnt vmcnt(3)" ::: "memory");
        } else {
            asm volatile("s_waitcnt vmcnt(0)" ::: "memory");
        }
        __builtin_amdgcn_s_barrier();

        bf16x8 af[MI], bfr[4];
#pragma unroll
        for (int i = 0; i < MI; ++i) af[i]  = *(const bf16x8*)&As[cur][(wm + i * 16 + l16) * 32 + (quad ^ rsw) * 8];
#pragma unroll
        for (int i = 0; i < 4; ++i)  bfr[i] = *(const bf16x8*)&Bs[cur][(wn + i * 16 + l16) * 32 + (quad ^ rsw) * 8];
#pragma unroll
        for (int i = 0; i < MI; ++i)
#pragma unroll
            for (int jn = 0; jn < 4; ++jn)
                acc[i][jn] = __builtin_amdgcn_mfma_f32_16x16x32_bf16(af[i], bfr[jn], acc[i][jn], 0, 0, 0);
        __builtin_amdgcn_s_barrier();
    }

    if (DO_VT && b == 2) {
#pragma unroll
        for (int i = 0; i < MI; ++i)
#pragma unroll
            for (int jn = 0; jn < 4; ++jn) {
                int n = n0 + wn + jn * 16 + l16;
                int m = m0 + wm + i * 16 + quad * 4;
                int sm = (m & ~31) | ((m & 12) << 1) | ((m & 16) >> 2) | (m & 3);
                u16x4 o;
#pragma unroll
                for (int r = 0; r < 4; ++r) o[r] = f2b(acc[i][jn][r]);
                *(u16x4*)&VT[(size_t)n * 2048 + sm] = o;
            }
    } else {
#pragma unroll
        for (int i = 0; i < MI; ++i)
#pragma unroll
            for (int jn = 0; jn < 4; ++jn)
#pragma unroll
                for (int r = 0; r < 4; ++r) {
                    int row = m0 + wm + i * 16 + quad * 4 + r;
                    int col = n0 + wn + jn * 16 + l16;
                    float v = acc[i][jn][r] * alpha;
                    if (OUT_BF16)
                        ((unsigned short*)Cbase + (size_t)b * 4194304)[(size_t)row * 2048 + col] = f2b(v);
                    else
                        ((float*)Cbase)[(size_t)row * 2048 + col] = v;
                }
    }
}

// ---------------- differential flash attention: K in LDS, V direct from L2 ----------------
// Vs dropped (L2-resident vt, pi-permuted -> PV A-frag is ONE contiguous 16B global load).
// LDS 64.5 -> 32.3 KB; 3 waves/SIMD. V-u0 prefetched at chunk top (covered by QK^T);
// V-u1 interleaved into PV-u0.
__global__ __launch_bounds__(256, 3) void diff_attn(const unsigned short* __restrict__ qb,
                                                    const unsigned short* __restrict__ kb,
                                                    const unsigned short* __restrict__ vt,
                                                    const float* __restrict__ lq1,
                                                    const float* __restrict__ lk1,
                                                    const float* __restrict__ lq2,
                                                    const float* __restrict__ lk2,
                                                    const float* __restrict__ g,
                                                    unsigned short* __restrict__ Aout) {
    __shared__ __align__(16) unsigned short Ks[2][64 * 128];   // [kv][d], 16B-block ^ (row&15) swizzle
    __shared__ float lam_s;
    const int tid = threadIdx.x, w = tid >> 6, lane = tid & 63;
    const int quad = lane >> 4, l16 = lane & 15;
    const int bid = blockIdx.x;
    const int wrk = (bid & 7) * 64 + (bid >> 3);   // XCD-contiguous work id
    const int j = wrk >> 5;                        // head-pair 0..15 (2 per XCD)
    const int q0 = (wrk & 31) * 64;                // q-tile

    if (tid < 64) {
        float p1 = lq1[tid] * lk1[tid];
        float p2 = lq2[tid] * lk2[tid];
        for (int off = 32; off; off >>= 1) { p1 += __shfl_xor(p1, off, 64); p2 += __shfl_xor(p2, off, 64); }
        if (tid == 0) lam_s = __expf(p1) - __expf(p2) + LAMBDA_INIT_F;
    }

    bf16x8 qf[2][2];
#pragma unroll
    for (int p = 0; p < 2; ++p)
#pragma unroll
        for (int dh = 0; dh < 2; ++dh)
            qf[p][dh] = *(const bf16x8*)&qb[(size_t)(q0 + w * 16 + l16) * 2048 + j * 128 + p * 64 + dh * 32 + quad * 8];

    f32x4 O[2][8];
#pragma unroll
    for (int p = 0; p < 2; ++p)
#pragma unroll
        for (int i = 0; i < 8; ++i)
#pragma unroll
            for (int r = 0; r < 4; ++r) O[p][i][r] = 0.f;
    float lsum[2] = {0.f, 0.f};

    const int srK = lane >> 4;
    // per-lane V source row base (d = dt*16 + l16) and column (quad*8 within pi-permuted 32-block)
    const unsigned short* vrow = vt + (size_t)(j * 128 + l16) * 2048 + quad * 8;

    auto STAGE_K = [&](int bsel, int kv0) {
#pragma unroll
        for (int t = 0; t < 4; ++t) {
            int rowK = w * 16 + t * 4 + srK;
            int cbsK = ((lane & 15) ^ (rowK & 15)) * 8;
            GLD16(kb + (size_t)(kv0 + rowK) * 2048 + j * 128 + cbsK, &Ks[bsel][(w * 16 + t * 4) * 128]);
        }
    };

    STAGE_K(0, 0);
    for (int c = 0; c < 32; ++c) {
        const int cur = c & 1;
        const int kv0 = c * 64;
        // V u=0 half: 8x 16B from L2 (pi-permuted vt) — covered by the QK^T phase
        bf16x8 vf0[8];
#pragma unroll
        for (int dt = 0; dt < 8; ++dt)
            vf0[dt] = *(const bf16x8*)&vrow[(size_t)dt * 16 * 2048 + kv0];
        if (c < 31) {
            STAGE_K(cur ^ 1, kv0 + 64);
            asm volatile("s_waitcnt vmcnt(12)" ::: "memory");  // K(c) resident; V-u0(8)+K(c+1)(4) in flight
        } else {
            asm volatile("s_waitcnt vmcnt(8)" ::: "memory");   // K(31) resident; V-u0 in flight
        }
        __builtin_amdgcn_s_barrier();

        // QK^T + exp2, packed bf16 B-fragments for the K=32 PV
        u32x4 pd[2][2];
#pragma unroll
        for (int p = 0; p < 2; ++p) {
#pragma unroll
            for (int i = 0; i < 4; ++i) {
                bf16x8 a0 = *(const bf16x8*)&Ks[cur][(i * 16 + l16) * 128 + ((p * 8 + quad) ^ l16) * 8];
                bf16x8 a1 = *(const bf16x8*)&Ks[cur][(i * 16 + l16) * 128 + ((p * 8 + 4 + quad) ^ l16) * 8];
                f32x4 s = {0.f, 0.f, 0.f, 0.f};
                s = __builtin_amdgcn_mfma_f32_16x16x32_bf16(a0, qf[p][0], s, 0, 0, 0);
                s = __builtin_amdgcn_mfma_f32_16x16x32_bf16(a1, qf[p][1], s, 0, 0, 0);
                float e0 = EXP2(s[0]), e1 = EXP2(s[1]), e2 = EXP2(s[2]), e3 = EXP2(s[3]);
                lsum[p] += (e0 + e1) + (e2 + e3);
                pd[p][i >> 1][(i & 1) * 2]     = pk2(e0, e1);
                pd[p][i >> 1][(i & 1) * 2 + 1] = pk2(e2, e3);
            }
        }
        // PV u=0 with interleaved u=1 loads (vf1[dt] issued as vf0[dt] dies)
        bf16x8 vf1[8];
#pragma unroll
        for (int dt = 0; dt < 8; ++dt) {
            vf1[dt] = *(const bf16x8*)&vrow[(size_t)dt * 16 * 2048 + kv0 + 32];
            O[0][dt] = __builtin_amdgcn_mfma_f32_16x16x32_bf16(vf0[dt], __builtin_bit_cast(bf16x8, pd[0][0]), O[0][dt], 0, 0, 0);
            O[1][dt] = __builtin_amdgcn_mfma_f32_16x16x32_bf16(vf0[dt], __builtin_bit_cast(bf16x8, pd[1][0]), O[1][dt], 0, 0, 0);
        }
#pragma unroll
        for (int dt = 0; dt < 8; ++dt) {
            O[0][dt] = __builtin_amdgcn_mfma_f32_16x16x32_bf16(vf1[dt], __builtin_bit_cast(bf16x8, pd[0][1]), O[0][dt], 0, 0, 0);
            O[1][dt] = __builtin_amdgcn_mfma_f32_16x16x32_bf16(vf1[dt], __builtin_bit_cast(bf16x8, pd[1][1]), O[1][dt], 0, 0, 0);
        }
        __builtin_amdgcn_s_barrier();   // all waves done reading Ks[cur] before restage at c+2
    }

#pragma unroll
    for (int p = 0; p < 2; ++p) {
        lsum[p] += __shfl_xor(lsum[p], 16, 64);
        lsum[p] += __shfl_xor(lsum[p], 32, 64);
    }
    const float inv1 = 1.0f / lsum[0];
    const float inv2 = lam_s / lsum[1];

    float ssum = 0.f;
#pragma unroll
    for (int dt = 0; dt < 8; ++dt)
#pragma unroll
        for (int r = 0; r < 4; ++r) {
            float v = O[0][dt][r] * inv1 - O[1][dt][r] * inv2;
            O[0][dt][r] = v;
            ssum += v * v;
        }
    ssum += __shfl_xor(ssum, 16, 64);
    ssum += __shfl_xor(ssum, 32, 64);
    const float rms = rsqrtf(ssum * (1.0f / 128.0f) + 1e-5f) * (1.0f - LAMBDA_INIT_F);

#pragma unroll
    for (int dt = 0; dt < 8; ++dt) {
        float4 g4 = *(const float4*)&g[dt * 16 + quad * 4];
        u16x4 o;
        o[0] = f2b(O[0][dt][0] * rms * g4.x);
        o[1] = f2b(O[0][dt][1] * rms * g4.y);
        o[2] = f2b(O[0][dt][2] * rms * g4.z);
        o[3] = f2b(O[0][dt][3] * rms * g4.w);
        *(u16x4*)&Aout[(size_t)(q0 + w * 16 + l16) * 2048 + j * 128 + dt * 16 + quad * 4] = o;
    }
}

extern "C" void kernel_launch(void* const* d_in, const int* in_sizes, int n_in,
                              void* d_out, int out_size, void* d_ws, size_t ws_size,
                              hipStream_t stream) {
    const float* query = (const float*)d_in[0];
    const float* key   = (const float*)d_in[1];
    const float* value = (const float*)d_in[2];
    const float* Wq  = (const float*)d_in[5];
    const float* Wk  = (const float*)d_in[6];
    const float* Wv  = (const float*)d_in[7];
    const float* Wo  = (const float*)d_in[8];
    const float* lq1 = (const float*)d_in[9];
    const float* lk1 = (const float*)d_in[10];
    const float* lq2 = (const float*)d_in[11];
    const float* lk2 = (const float*)d_in[12];
    const float* g   = (const float*)d_in[13];

    char* ws = (char*)d_ws;
    const size_t MB = 1ull << 20;
    const size_t N4 = 4194304;  // 2048*2048
    unsigned short* qb  = (unsigned short*)(ws + 0 * MB);    // qb,kb contiguous (GEMM out z=0,1)
    unsigned short* vt  = (unsigned short*)(ws + 16 * MB);   // V^T (z=2 transposed epilogue, pi-permuted kv)
    unsigned short* Aat = (unsigned short*)(ws + 24 * MB);
    unsigned short* Xq  = (unsigned short*)(ws + 32 * MB);   // Xq,Xk,Xv then Wq,Wk,Wv,Wo: 7 contiguous slabs

    // alpha = HD^-0.5 * log2(e): scores come out in log2 domain -> raw v_exp_f32 in diff_attn
    const float alpha_q = 0.125f * 1.44269504f;

    cvt7<<<dim3(2048, 7), dim3(256), 0, stream>>>(query, key, value, Wq, Wk, Wv, Wo, Xq);
    // q/k/v projections: 256^2 tiles, round-6 4-phase GLD16 schedule (verified 66.5 us)
    gemm_qkv<<<dim3(192), dim3(512), 0, stream>>>(Xq, Xq + 3 * N4, qb, vt, alpha_q);
    diff_attn<<<dim3(512), dim3(256), 0, stream>>>(qb, qb + N4, vt, lq1, lk1, lq2, lk2, g, Aat);
    // output projection: 128x128 tiles -> 256 blocks (higher intensity than NT=64)
    gemm_bt<0, 128, 0, 3><<<dim3(16, 16, 1), dim3(256), 0, stream>>>(Aat, Xq + 6 * N4, d_out, nullptr, 1.0f);
}

// Round 11
// 299.683 us; speedup vs baseline: 1.4938x; 1.4938x over previous
//
#include <hip/hip_runtime.h>
#include <stdint.h>

#define LAMBDA_INIT_F 0.7836057665f   // 0.8 - 0.6*exp(-0.3*12)

typedef __bf16 bf16x8 __attribute__((ext_vector_type(8)));
typedef float  f32x4  __attribute__((ext_vector_type(4)));
typedef unsigned short u16x8 __attribute__((ext_vector_type(8)));
typedef unsigned short u16x4 __attribute__((ext_vector_type(4)));
typedef unsigned int u32x4 __attribute__((ext_vector_type(4)));

__device__ __forceinline__ unsigned short f2b(float f) {
    union { float f; unsigned u; } v; v.f = f;
    unsigned u = v.u;
    return (unsigned short)((u + 0x7fffu + ((u >> 16) & 1u)) >> 16);
}

// pack two fp32 -> two bf16 (round-half-up) in one dword: [bf(b):bf(a)]
__device__ __forceinline__ unsigned pk2(float a, float b) {
    unsigned ua = __float_as_uint(a) + 0x8000u;
    unsigned ub = __float_as_uint(b) + 0x8000u;
    return __builtin_amdgcn_perm(ub, ua, 0x07060302u);
}

#if __has_builtin(__builtin_amdgcn_exp2f)
#define EXP2(x) __builtin_amdgcn_exp2f(x)
#else
__device__ __forceinline__ float EXP2(float x) {
    float r; asm volatile("v_exp_f32 %0, %1\n\ts_nop 1" : "=v"(r) : "v"(x)); return r;
}
#endif

// global(16B/lane) -> LDS direct. LDS base must be wave-uniform; lanes land at base + lane*16.
#define GLD16(gp, sp) __builtin_amdgcn_global_load_lds( \
    (const __attribute__((address_space(1))) void*)(uintptr_t)(gp), \
    (__attribute__((address_space(3))) void*)(uint32_t)(uintptr_t)(sp), 16, 0, 0)

// ---------------- fp32 -> bf16 convert, 7 slabs of 4M elements ----------------
__global__ __launch_bounds__(256) void cvt7(const float* __restrict__ s0, const float* __restrict__ s1,
                                            const float* __restrict__ s2, const float* __restrict__ s3,
                                            const float* __restrict__ s4, const float* __restrict__ s5,
                                            const float* __restrict__ s6,
                                            unsigned short* __restrict__ dst) {
    int z = blockIdx.y;
    const float* s = z == 0 ? s0 : z == 1 ? s1 : z == 2 ? s2 : z == 3 ? s3 : z == 4 ? s4 : z == 5 ? s5 : s6;
    unsigned short* d = dst + (size_t)z * 4194304;
    size_t i = ((size_t)blockIdx.x * 256 + threadIdx.x) * 8;
    float4 a = *(const float4*)(s + i);
    float4 b = *(const float4*)(s + i + 4);
    u16x8 o;
    o[0] = f2b(a.x); o[1] = f2b(a.y); o[2] = f2b(a.z); o[3] = f2b(a.w);
    o[4] = f2b(b.x); o[5] = f2b(b.y); o[6] = f2b(b.z); o[7] = f2b(b.w);
    *(u16x8*)(d + i) = o;
}

// ---------------- QKV projection: 256x256 tile, BK=64, 8 waves, m201-style 4-phase ----------------
// ROUND-6 VERSION (verified 66.5 us): bf16 inputs via GLD16, single-buffered 64 KiB LDS,
// staging halves grouped by death time, counted vmcnt, per-phase barriers, setprio MFMA clusters.
__global__ __launch_bounds__(512, 2) void gemm_qkv(const unsigned short* __restrict__ Abase,
                                                   const unsigned short* __restrict__ Bbase,
                                                   unsigned short* __restrict__ Cb,
                                                   unsigned short* __restrict__ VT,
                                                   float alpha0) {
    __shared__ __align__(16) unsigned short As[16384];   // [kk*8192 + row*32 + col], 64B rows
    __shared__ __align__(16) unsigned short Bs[16384];
    const int tid = threadIdx.x;
    const int wid = tid >> 6, lane = tid & 63;
    const int quad = lane >> 4, l16 = lane & 15;
    const int wr = wid >> 2, wc = wid & 3;                 // wave grid 2M x 4N
    const int bid = blockIdx.x;
    const int wrk = (bid & 7) * 24 + (bid >> 3);           // bijective XCD swizzle (192 = 8*24)
    const int z = wrk >> 6;
    const int t6 = wrk & 63;
    const int m0 = (t6 >> 3) * 256, n0 = (t6 & 7) * 256;
    const unsigned short* A = Abase + (size_t)z * 4194304;
    const unsigned short* B = Bbase + (size_t)z * 4194304;
    const float alpha = (z == 0) ? alpha0 : 1.0f;

    const int sr = lane >> 2;                              // 0..15 row within 16-row slab
    const int sc = (((lane & 3) ^ ((lane >> 3) & 3)) * 8); // swizzled global colblock
    const int rsw = ((l16 >> 1) & 3);                      // read-side swizzle key

    f32x4 acc[8][4];
#pragma unroll
    for (int mi = 0; mi < 8; ++mi)
#pragma unroll
        for (int ni = 0; ni < 4; ++ni) acc[mi][ni] = f32x4{0.f, 0.f, 0.f, 0.f};

    // A-half h: rows (wid>>2)*128 + (wid&3)*16 + h*64, both kk subtiles (2 gld/thread)
    auto STAGE_AH = [&](int h, int k0) {
        const int rowbase = (wid >> 2) * 128 + (wid & 3) * 16 + h * 64;
#pragma unroll
        for (int kk = 0; kk < 2; ++kk)
            GLD16(A + (size_t)(m0 + rowbase + sr) * 2048 + k0 + kk * 32 + sc, &As[(kk * 256 + rowbase) * 32]);
    };
    // B-half h: rows (wid>>1)*64 + (wid&1)*16 + h*32
    auto STAGE_BH = [&](int h, int k0) {
        const int rowbase = (wid >> 1) * 64 + (wid & 1) * 16 + h * 32;
#pragma unroll
        for (int kk = 0; kk < 2; ++kk)
            GLD16(B + (size_t)(n0 + rowbase + sr) * 2048 + k0 + kk * 32 + sc, &Bs[(kk * 256 + rowbase) * 32]);
    };

#define LD_A(mh, i, kk) (*(const bf16x8*)&As[(kk * 256 + wr * 128 + (mh) * 64 + (i) * 16 + l16) * 32 + (quad ^ rsw) * 8])
#define LD_B(nh, jn, kk) (*(const bf16x8*)&Bs[(kk * 256 + wc * 64 + (nh) * 32 + (jn) * 16 + l16) * 32 + (quad ^ rsw) * 8])

    // prologue: stage tile 0 in queue order Ah0,Bh0 (oldest 4) then Bh1, Ah1
    STAGE_AH(0, 0); STAGE_BH(0, 0);
    STAGE_BH(1, 0);
    STAGE_AH(1, 0);
    asm volatile("s_waitcnt vmcnt(4)" ::: "memory");   // Ah0,Bh0 resident; Bh1,Ah1 in flight
    __builtin_amdgcn_s_barrier();

    for (int kt = 0; kt < 32; ++kt) {
        const int k1 = (kt + 1) * 64;
        bf16x8 af[2][4], b0[2][2], b1[2][2];

        // ---- P1: reads Ah0+Bh0(kt); MFMA quadrant (0,0); no staging
#pragma unroll
        for (int kk = 0; kk < 2; ++kk) {
#pragma unroll
            for (int i = 0; i < 4; ++i) af[kk][i] = LD_A(0, i, kk);
#pragma unroll
            for (int jn = 0; jn < 2; ++jn) b0[kk][jn] = LD_B(0, jn, kk);
        }
        __builtin_amdgcn_s_barrier();
        __builtin_amdgcn_s_setprio(1);
#pragma unroll
        for (int i = 0; i < 4; ++i)
#pragma unroll
            for (int jn = 0; jn < 2; ++jn)
#pragma unroll
                for (int kk = 0; kk < 2; ++kk)
                    acc[i][jn] = __builtin_amdgcn_mfma_f32_16x16x32_bf16(af[kk][i], b0[kk][jn], acc[i][jn], 0, 0, 0);
        __builtin_amdgcn_s_setprio(0);
        asm volatile("s_waitcnt vmcnt(2)" ::: "memory");   // Bh1(kt) resident for P2
        __builtin_amdgcn_s_barrier();

        // ---- P2: reads Bh1(kt); stage Ah0,Bh0(kt+1) into dead regions; MFMA (0,1)
#pragma unroll
        for (int kk = 0; kk < 2; ++kk)
#pragma unroll
            for (int jn = 0; jn < 2; ++jn) b1[kk][jn] = LD_B(1, jn, kk);
        if (kt < 31) { STAGE_AH(0, k1); STAGE_BH(0, k1); }
        __builtin_amdgcn_s_barrier();
        __builtin_amdgcn_s_setprio(1);
#pragma unroll
        for (int i = 0; i < 4; ++i)
#pragma unroll
            for (int jn = 0; jn < 2; ++jn)
#pragma unroll
                for (int kk = 0; kk < 2; ++kk)
                    acc[i][2 + jn] = __builtin_amdgcn_mfma_f32_16x16x32_bf16(af[kk][i], b1[kk][jn], acc[i][2 + jn], 0, 0, 0);
        __builtin_amdgcn_s_setprio(0);
        if (kt < 31) asm volatile("s_waitcnt vmcnt(4)" ::: "memory");  // Ah1(kt) resident for P3
        else         asm volatile("s_waitcnt vmcnt(0)" ::: "memory");
        __builtin_amdgcn_s_barrier();

        // ---- P3: reads Ah1(kt); stage Bh1(kt+1); MFMA (1,1)
#pragma unroll
        for (int kk = 0; kk < 2; ++kk)
#pragma unroll
            for (int i = 0; i < 4; ++i) af[kk][i] = LD_A(1, i, kk);
        if (kt < 31) STAGE_BH(1, k1);
        __builtin_amdgcn_s_barrier();
        __builtin_amdgcn_s_setprio(1);
#pragma unroll
        for (int i = 0; i < 4; ++i)
#pragma unroll
            for (int jn = 0; jn < 2; ++jn)
#pragma unroll
                for (int kk = 0; kk < 2; ++kk)
                    acc[4 + i][2 + jn] = __builtin_amdgcn_mfma_f32_16x16x32_bf16(af[kk][i], b1[kk][jn], acc[4 + i][2 + jn], 0, 0, 0);
        __builtin_amdgcn_s_setprio(0);
        __builtin_amdgcn_s_barrier();

        // ---- P4: register-only MFMA (1,0); stage Ah1(kt+1)
        if (kt < 31) STAGE_AH(1, k1);
        __builtin_amdgcn_s_barrier();
        __builtin_amdgcn_s_setprio(1);
#pragma unroll
        for (int i = 0; i < 4; ++i)
#pragma unroll
            for (int jn = 0; jn < 2; ++jn)
#pragma unroll
                for (int kk = 0; kk < 2; ++kk)
                    acc[4 + i][jn] = __builtin_amdgcn_mfma_f32_16x16x32_bf16(af[kk][i], b0[kk][jn], acc[4 + i][jn], 0, 0, 0);
        __builtin_amdgcn_s_setprio(0);
        asm volatile("s_waitcnt vmcnt(4)" ::: "memory");   // Ah0,Bh0(kt+1) resident for next P1
        __builtin_amdgcn_s_barrier();
    }
#undef LD_A
#undef LD_B

    if (z == 2) {
        // transposed write: VT[n][pi(m)], packed 4 bf16 (m-consecutive, pi keeps low 2 bits)
#pragma unroll
        for (int mi = 0; mi < 8; ++mi)
#pragma unroll
            for (int ni = 0; ni < 4; ++ni) {
                int n = n0 + wc * 64 + ni * 16 + l16;
                int m = m0 + wr * 128 + mi * 16 + quad * 4;
                int sm = (m & ~31) | ((m & 12) << 1) | ((m & 16) >> 2) | (m & 3);
                u16x4 o;
#pragma unroll
                for (int r = 0; r < 4; ++r) o[r] = f2b(acc[mi][ni][r]);
                *(u16x4*)&VT[(size_t)n * 2048 + sm] = o;
            }
    } else {
        unsigned short* Cz = Cb + (size_t)z * 4194304;
#pragma unroll
        for (int mi = 0; mi < 8; ++mi)
#pragma unroll
            for (int ni = 0; ni < 4; ++ni)
#pragma unroll
                for (int r = 0; r < 4; ++r) {
                    int row = m0 + wr * 128 + mi * 16 + quad * 4 + r;
                    int col = n0 + wc * 64 + ni * 16 + l16;
                    Cz[(size_t)row * 2048 + col] = f2b(acc[mi][ni][r] * alpha);
                }
    }
}

// ---------------- output projection GEMM (NT=128 tile, triple-buffered) ----------------
template <int OUT_BF16, int NT, int DO_VT, int WPB>
__global__ __launch_bounds__(256, WPB) void gemm_bt(const unsigned short* __restrict__ Abase,
                                                    const unsigned short* __restrict__ Bbase,
                                                    void* __restrict__ Cbase,
                                                    unsigned short* __restrict__ VT,
                                                    float alpha0) {
    constexpr int MI = (NT == 128) ? 4 : 2;
    __shared__ __align__(16) unsigned short As[3][128 * 32];
    __shared__ __align__(16) unsigned short Bs[3][NT * 32];
    const int tid = threadIdx.x;
    const int w = tid >> 6, lane = tid & 63;
    const int quad = lane >> 4, l16 = lane & 15;
    const int b = blockIdx.z;
    const unsigned short* A = Abase + (size_t)b * 4194304;
    const unsigned short* B = Bbase + (size_t)b * 4194304;
    const float alpha = (b == 0) ? alpha0 : 1.0f;
    const int m0 = blockIdx.y * 128, n0 = blockIdx.x * NT;
    const int wm = (NT == 128) ? (w >> 1) * 64 : w * 32;
    const int wn = (NT == 128) ? (w & 1) * 64 : 0;
    const int sr = lane >> 2;                              // 0..15 row within 16-row slab
    const int sc = (((lane & 3) ^ ((lane >> 3) & 3)) * 8); // swizzled global colblock
    const int rsw = ((l16 >> 1) & 3);                      // read-side swizzle key

    f32x4 zz = {0.f, 0.f, 0.f, 0.f};
    f32x4 acc[MI][4];
#pragma unroll
    for (int i = 0; i < MI; ++i)
#pragma unroll
        for (int jn = 0; jn < 4; ++jn) acc[i][jn] = zz;

    auto STAGE = [&](int bsel, int k0) {
        GLD16(A + (size_t)(m0 + w * 16 + sr) * 2048 + k0 + sc,      &As[bsel][(w * 16) * 32]);
        GLD16(A + (size_t)(m0 + 64 + w * 16 + sr) * 2048 + k0 + sc, &As[bsel][(64 + w * 16) * 32]);
        if (NT == 128) {
            GLD16(B + (size_t)(n0 + w * 16 + sr) * 2048 + k0 + sc,      &Bs[bsel][(w * 16) * 32]);
            GLD16(B + (size_t)(n0 + 64 + w * 16 + sr) * 2048 + k0 + sc, &Bs[bsel][(64 + w * 16) * 32]);
        } else {
            GLD16(B + (size_t)(n0 + w * 16 + sr) * 2048 + k0 + sc, &Bs[bsel][(w * 16) * 32]);
        }
    };

    STAGE(0, 0);
    STAGE(1, 32);
    for (int c = 0; c < 64; ++c) {
        const int cur = c % 3;
        if (c < 62) {
            STAGE((c + 2) % 3, (c + 2) * 32);
            if (NT == 128) asm volatile("s_waitcnt vmcnt(8)" ::: "memory");
            else           asm volatile("s_waitcnt vmcnt(6)" ::: "memory");
        } else if (c == 62) {
            if (NT == 128) asm volatile("s_waitcnt vmcnt(4)" ::: "memory");
            else           asm volatile("s_waitcnt vmcnt(3)" ::: "memory");
        } else {
            asm volatile("s_waitcnt vmcnt(0)" ::: "memory");
        }
        __builtin_amdgcn_s_barrier();

        bf16x8 af[MI], bfr[4];
#pragma unroll
        for (int i = 0; i < MI; ++i) af[i]  = *(const bf16x8*)&As[cur][(wm + i * 16 + l16) * 32 + (quad ^ rsw) * 8];
#pragma unroll
        for (int i = 0; i < 4; ++i)  bfr[i] = *(const bf16x8*)&Bs[cur][(wn + i * 16 + l16) * 32 + (quad ^ rsw) * 8];
#pragma unroll
        for (int i = 0; i < MI; ++i)
#pragma unroll
            for (int jn = 0; jn < 4; ++jn)
                acc[i][jn] = __builtin_amdgcn_mfma_f32_16x16x32_bf16(af[i], bfr[jn], acc[i][jn], 0, 0, 0);
        __builtin_amdgcn_s_barrier();
    }

    if (DO_VT && b == 2) {
#pragma unroll
        for (int i = 0; i < MI; ++i)
#pragma unroll
            for (int jn = 0; jn < 4; ++jn) {
                int n = n0 + wn + jn * 16 + l16;
                int m = m0 + wm + i * 16 + quad * 4;
                int sm = (m & ~31) | ((m & 12) << 1) | ((m & 16) >> 2) | (m & 3);
                u16x4 o;
#pragma unroll
                for (int r = 0; r < 4; ++r) o[r] = f2b(acc[i][jn][r]);
                *(u16x4*)&VT[(size_t)n * 2048 + sm] = o;
            }
    } else {
#pragma unroll
        for (int i = 0; i < MI; ++i)
#pragma unroll
            for (int jn = 0; jn < 4; ++jn)
#pragma unroll
                for (int r = 0; r < 4; ++r) {
                    int row = m0 + wm + i * 16 + quad * 4 + r;
                    int col = n0 + wn + jn * 16 + l16;
                    float v = acc[i][jn][r] * alpha;
                    if (OUT_BF16)
                        ((unsigned short*)Cbase + (size_t)b * 4194304)[(size_t)row * 2048 + col] = f2b(v);
                    else
                        ((float*)Cbase)[(size_t)row * 2048 + col] = v;
                }
    }
}

// ---------------- differential flash attention, S^T register path (round-6 version) ----------------
// K and V double-buffered in LDS; counted vmcnt(8) + raw barriers; PV at K=32 with
// sigma(8q+j) = 16*(j>>2)+4q+(j&3); V^T stored pi-permuted -> A-fragment is one b128 read.
__global__ __launch_bounds__(256, 2) void diff_attn(const unsigned short* __restrict__ qb,
                                                    const unsigned short* __restrict__ kb,
                                                    const unsigned short* __restrict__ vt,
                                                    const float* __restrict__ lq1,
                                                    const float* __restrict__ lk1,
                                                    const float* __restrict__ lq2,
                                                    const float* __restrict__ lk2,
                                                    const float* __restrict__ g,
                                                    unsigned short* __restrict__ Aout) {
    __shared__ __align__(16) unsigned short Ks[2][64 * 128];   // [kv][d], 16B-block ^ (row&15) swizzle
    __shared__ __align__(16) unsigned short Vs[2][128 * 64];   // [d][pi(kv)], 16B-block ^ (row&7) swizzle
    __shared__ float lam_s;
    const int tid = threadIdx.x, w = tid >> 6, lane = tid & 63;
    const int quad = lane >> 4, l16 = lane & 15;
    const int bid = blockIdx.x;
    const int wrk = (bid & 7) * 64 + (bid >> 3);   // XCD-contiguous work id
    const int j = wrk >> 5;                        // head-pair 0..15 (2 per XCD)
    const int q0 = (wrk & 31) * 64;                // q-tile

    if (tid < 64) {
        float p1 = lq1[tid] * lk1[tid];
        float p2 = lq2[tid] * lk2[tid];
        for (int off = 32; off; off >>= 1) { p1 += __shfl_xor(p1, off, 64); p2 += __shfl_xor(p2, off, 64); }
        if (tid == 0) lam_s = __expf(p1) - __expf(p2) + LAMBDA_INIT_F;
    }

    bf16x8 qf[2][2];
#pragma unroll
    for (int p = 0; p < 2; ++p)
#pragma unroll
        for (int dh = 0; dh < 2; ++dh)
            qf[p][dh] = *(const bf16x8*)&qb[(size_t)(q0 + w * 16 + l16) * 2048 + j * 128 + p * 64 + dh * 32 + quad * 8];

    f32x4 O[2][8];
#pragma unroll
    for (int p = 0; p < 2; ++p)
#pragma unroll
        for (int i = 0; i < 8; ++i)
#pragma unroll
            for (int r = 0; r < 4; ++r) O[p][i][r] = 0.f;
    float lsum[2] = {0.f, 0.f};

    const int srK = lane >> 4;
    const int srV = lane >> 3;
    const int scV = ((lane & 7) ^ (lane >> 3)) * 8;

    auto STAGE = [&](int bsel, int kv0) {
#pragma unroll
        for (int t = 0; t < 4; ++t) {
            int rowK = w * 16 + t * 4 + srK;
            int cbsK = ((lane & 15) ^ (rowK & 15)) * 8;
            GLD16(kb + (size_t)(kv0 + rowK) * 2048 + j * 128 + cbsK, &Ks[bsel][(w * 16 + t * 4) * 128]);
        }
#pragma unroll
        for (int t = 0; t < 4; ++t) {
            int rowV = w * 32 + t * 8 + srV;
            GLD16(vt + (size_t)(j * 128 + rowV) * 2048 + kv0 + scV, &Vs[bsel][(w * 32 + t * 8) * 64]);
        }
    };

    STAGE(0, 0);
    for (int c = 0; c < 32; ++c) {
        const int cur = c & 1;
        if (c < 31) {
            STAGE(cur ^ 1, (c + 1) * 64);
            asm volatile("s_waitcnt vmcnt(8)" ::: "memory");
        } else {
            asm volatile("s_waitcnt vmcnt(0)" ::: "memory");
        }
        __builtin_amdgcn_s_barrier();

        u32x4 pd[2][2];
#pragma unroll
        for (int p = 0; p < 2; ++p) {
#pragma unroll
            for (int i = 0; i < 4; ++i) {
                bf16x8 a0 = *(const bf16x8*)&Ks[cur][(i * 16 + l16) * 128 + ((p * 8 + quad) ^ l16) * 8];
                bf16x8 a1 = *(const bf16x8*)&Ks[cur][(i * 16 + l16) * 128 + ((p * 8 + 4 + quad) ^ l16) * 8];
                f32x4 s = {0.f, 0.f, 0.f, 0.f};
                s = __builtin_amdgcn_mfma_f32_16x16x32_bf16(a0, qf[p][0], s, 0, 0, 0);
                s = __builtin_amdgcn_mfma_f32_16x16x32_bf16(a1, qf[p][1], s, 0, 0, 0);
                float e0 = EXP2(s[0]), e1 = EXP2(s[1]), e2 = EXP2(s[2]), e3 = EXP2(s[3]);
                lsum[p] += (e0 + e1) + (e2 + e3);
                pd[p][i >> 1][(i & 1) * 2]     = pk2(e0, e1);
                pd[p][i >> 1][(i & 1) * 2 + 1] = pk2(e2, e3);
            }
        }
#pragma unroll
        for (int u = 0; u < 2; ++u) {
            const int blk = (((4 * u + quad) ^ (l16 & 7))) * 8;
#pragma unroll
            for (int dt = 0; dt < 8; ++dt) {
                bf16x8 vf8 = *(const bf16x8*)&Vs[cur][(dt * 16 + l16) * 64 + blk];
                O[0][dt] = __builtin_amdgcn_mfma_f32_16x16x32_bf16(vf8, __builtin_bit_cast(bf16x8, pd[0][u]), O[0][dt], 0, 0, 0);
                O[1][dt] = __builtin_amdgcn_mfma_f32_16x16x32_bf16(vf8, __builtin_bit_cast(bf16x8, pd[1][u]), O[1][dt], 0, 0, 0);
            }
        }
        __builtin_amdgcn_s_barrier();
    }

#pragma unroll
    for (int p = 0; p < 2; ++p) {
        lsum[p] += __shfl_xor(lsum[p], 16, 64);
        lsum[p] += __shfl_xor(lsum[p], 32, 64);
    }
    const float inv1 = 1.0f / lsum[0];
    const float inv2 = lam_s / lsum[1];

    float ssum = 0.f;
#pragma unroll
    for (int dt = 0; dt < 8; ++dt)
#pragma unroll
        for (int r = 0; r < 4; ++r) {
            float v = O[0][dt][r] * inv1 - O[1][dt][r] * inv2;
            O[0][dt][r] = v;
            ssum += v * v;
        }
    ssum += __shfl_xor(ssum, 16, 64);
    ssum += __shfl_xor(ssum, 32, 64);
    const float rms = rsqrtf(ssum * (1.0f / 128.0f) + 1e-5f) * (1.0f - LAMBDA_INIT_F);

#pragma unroll
    for (int dt = 0; dt < 8; ++dt) {
        float4 g4 = *(const float4*)&g[dt * 16 + quad * 4];
        u16x4 o;
        o[0] = f2b(O[0][dt][0] * rms * g4.x);
        o[1] = f2b(O[0][dt][1] * rms * g4.y);
        o[2] = f2b(O[0][dt][2] * rms * g4.z);
        o[3] = f2b(O[0][dt][3] * rms * g4.w);
        *(u16x4*)&Aout[(size_t)(q0 + w * 16 + l16) * 2048 + j * 128 + dt * 16 + quad * 4] = o;
    }
}

extern "C" void kernel_launch(void* const* d_in, const int* in_sizes, int n_in,
                              void* d_out, int out_size, void* d_ws, size_t ws_size,
                              hipStream_t stream) {
    const float* query = (const float*)d_in[0];
    const float* key   = (const float*)d_in[1];
    const float* value = (const float*)d_in[2];
    const float* Wq  = (const float*)d_in[5];
    const float* Wk  = (const float*)d_in[6];
    const float* Wv  = (const float*)d_in[7];
    const float* Wo  = (const float*)d_in[8];
    const float* lq1 = (const float*)d_in[9];
    const float* lk1 = (const float*)d_in[10];
    const float* lq2 = (const float*)d_in[11];
    const float* lk2 = (const float*)d_in[12];
    const float* g   = (const float*)d_in[13];

    char* ws = (char*)d_ws;
    const size_t MB = 1ull << 20;
    const size_t N4 = 4194304;  // 2048*2048
    unsigned short* qb  = (unsigned short*)(ws + 0 * MB);    // qb,kb contiguous (GEMM out z=0,1)
    unsigned short* vt  = (unsigned short*)(ws + 16 * MB);   // V^T (z=2 transposed epilogue, pi-permuted kv)
    unsigned short* Aat = (unsigned short*)(ws + 24 * MB);
    unsigned short* Xq  = (unsigned short*)(ws + 32 * MB);   // Xq,Xk,Xv then Wq,Wk,Wv,Wo: 7 contiguous slabs

    // alpha = HD^-0.5 * log2(e): scores come out in log2 domain -> raw v_exp_f32 in diff_attn
    const float alpha_q = 0.125f * 1.44269504f;

    cvt7<<<dim3(2048, 7), dim3(256), 0, stream>>>(query, key, value, Wq, Wk, Wv, Wo, Xq);
    // q/k/v projections: 256^2 tiles, round-6 4-phase GLD16 schedule (verified 66.5 us)
    gemm_qkv<<<dim3(192), dim3(512), 0, stream>>>(Xq, Xq + 3 * N4, qb, vt, alpha_q);
    // attention: round-6 version (verified 66.6 us, no spill)
    diff_attn<<<dim3(512), dim3(256), 0, stream>>>(qb, qb + N4, vt, lq1, lk1, lq2, lk2, g, Aat);
    // output projection: 128x128 tiles -> 256 blocks (proven 23 us/slab at this config, round 3)
    gemm_bt<0, 128, 0, 3><<<dim3(16, 16, 1), dim3(256), 0, stream>>>(Aat, Xq + 6 * N4, d_out, nullptr, 1.0f);
}